// Round 11
// baseline (172.946 us; speedup 1.0000x reference)
//
#include <hip/hip_runtime.h>
#include <stdint.h>

#define SEQ 4096
#define DIM 128
#define NHEADS 8
#define HDK 16

typedef __bf16 bf16x2 __attribute__((ext_vector_type(2)));
typedef __bf16 bf16x8 __attribute__((ext_vector_type(8)));
typedef float f32x16 __attribute__((ext_vector_type(16)));
typedef float f32x4 __attribute__((ext_vector_type(4)));
typedef unsigned uint2v __attribute__((ext_vector_type(2)));
typedef unsigned uint4v __attribute__((ext_vector_type(4)));

__device__ inline unsigned short f2bf(float x) {
  unsigned u = __builtin_bit_cast(unsigned, x);
  u = (u + 0x7FFFu + ((u >> 16) & 1u)) >> 16;
  return (unsigned short)u;
}
__device__ inline unsigned pkbf(float lo, float hi) {
  return (unsigned)f2bf(lo) | ((unsigned)f2bf(hi) << 16);
}
// native RNE casts; compiler fuses pairs into v_cvt_pk_bf16_f32
__device__ inline unsigned pkbf_fast(float lo, float hi) {
  bf16x2 t;
  t[0] = (__bf16)lo;
  t[1] = (__bf16)hi;
  return __builtin_bit_cast(unsigned, t);
}
__device__ inline float fexp2(float x) {
#if __has_builtin(__builtin_amdgcn_exp2f)
  return __builtin_amdgcn_exp2f(x);
#else
  return exp2f(x);
#endif
}
// e if bit kvc of mrs clear, else 0  (sbfe + andn)
__device__ inline float apply_keep(float e, unsigned mrs, int kvc) {
#if __has_builtin(__builtin_amdgcn_sbfe)
  const unsigned m = (unsigned)__builtin_amdgcn_sbfe((int)mrs, kvc, 1);
#else
  const unsigned m = (unsigned)(((int)(mrs << (31 - kvc))) >> 31);
#endif
  return __builtin_bit_cast(float, __builtin_bit_cast(unsigned, e) & ~m);
}

// ---------------- kernel 0: fused pre-processing ---------------------------
// One dispatch, three block roles (overlapping VALU-heavy proj with the
// HBM-heavy mask stream instead of serializing two launches):
//   blocks   0..383 : projections (mat = bid>>7: Qp scaled / Kp / Vt32 ch<16)
//   blocks 384..895 : mask -> packed bits transpose (thread-owns-word, no
//                     ballots); bits[b][kt][row], bit kv = mask[b][row][kt*32+kv]
//   blocks 896..899 : Vt32 channel-16 init = 1.0 (lsum row; ch 17..31 never read)
__global__ __launch_bounds__(256) void k_pre(
    const float* __restrict__ qin, const float* __restrict__ hin,
    const float* __restrict__ Wq, const float* __restrict__ Wk,
    const float* __restrict__ Wv, const void* __restrict__ maskp,
    unsigned short* __restrict__ Qp, unsigned short* __restrict__ Kp,
    unsigned short* __restrict__ Vt32, unsigned* __restrict__ bits) {
  __shared__ float Wl[128][128];
  __shared__ float inl[8][128];
  const int bid = (int)blockIdx.x;
  const int tid = threadIdx.x;

  if (bid >= 896) {                    // ---- Vt32 ones-row init
    unsigned* Vt32w = (unsigned*)Vt32;
    const int base = (bid - 896) * 256 + tid;     // 0..1023
    #pragma unroll
    for (int j = 0; j < 32; ++j) {
      const int w = base + j * 1024;
      const int bh = w >> 11, n2 = w & 2047;
      Vt32w[((size_t)bh * 32 + 16) * 2048 + n2] = 0x3F803F80u;  // bf16 {1,1}
    }
    return;
  }

  if (bid >= 384) {                    // ---- mask transpose (ILP, no ballots)
    unsigned (*mlds)[17] = (unsigned (*)[17])Wl;  // 8.7KB overlay on Wl
    const unsigned*      mw = (const unsigned*)maskp;
    const unsigned char* m8 = (const unsigned char*)maskp;
    bool wordmode = true;
    #pragma unroll
    for (int i = 0; i < 32; ++i) {
      unsigned w = mw[i];
      if (!(w == 0u || w == 1u || w == 0x3F800000u)) wordmode = false;
    }
    const int mb = bid - 384;                      // 0..511
    const int b = mb >> 8;
    const int rowbase = (mb & 255) * 16;
    const int kt = tid & 127;
    #pragma unroll
    for (int p = 0; p < 8; ++p) {
      const int rl = p * 2 + (tid >> 7);           // 0..15
      const size_t g = ((size_t)b * SEQ + rowbase + rl) * SEQ + kt * 32;
      unsigned word = 0;
      if (wordmode) {
        uint4v w0 = *(const uint4v*)(mw + g);
        uint4v w1 = *(const uint4v*)(mw + g + 4);
        uint4v w2 = *(const uint4v*)(mw + g + 8);
        uint4v w3 = *(const uint4v*)(mw + g + 12);
        uint4v w4 = *(const uint4v*)(mw + g + 16);
        uint4v w5 = *(const uint4v*)(mw + g + 20);
        uint4v w6 = *(const uint4v*)(mw + g + 24);
        uint4v w7 = *(const uint4v*)(mw + g + 28);
        const uint4v wv[8] = { w0, w1, w2, w3, w4, w5, w6, w7 };
        #pragma unroll
        for (int j = 0; j < 8; ++j)
          #pragma unroll
          for (int e = 0; e < 4; ++e) {
            const unsigned w = wv[j][e];
            word |= ((w | (0u - w)) >> 31) << (4 * j + e);   // (w!=0)
          }
      } else {
        uint4v c0 = *(const uint4v*)(m8 + g);
        uint4v c1 = *(const uint4v*)(m8 + g + 16);
        const uint4v cv[2] = { c0, c1 };
        #pragma unroll
        for (int j = 0; j < 2; ++j)
          #pragma unroll
          for (int e = 0; e < 4; ++e) {
            unsigned w = cv[j][e];
            #pragma unroll
            for (int by = 0; by < 4; ++by) {
              word |= ((w & 0xFFu) ? 1u : 0u) << (16 * j + 4 * e + by);
              w >>= 8;
            }
          }
      }
      mlds[kt][rl] = word;
    }
    __syncthreads();
    #pragma unroll
    for (int j = 0; j < 8; ++j) {
      const int idx = tid + 256 * j;
      const int k2 = idx >> 4, rl = idx & 15;
      bits[((size_t)b * 128 + k2) * SEQ + rowbase + rl] = mlds[k2][rl];
    }
    return;
  }

  // ---- projections: Qp[b][n][h*16+k] (scaled), Kp[...], Vt32[b*8+h][v][n]
  const int mat = bid >> 7;            // 0,1,2
  const int xb  = bid & 127;
  const float* in = (mat == 0) ? qin : hin;
  const float* W  = (mat == 0) ? Wq : (mat == 1 ? Wk : Wv);
  for (int e = tid; e < 128 * 128; e += 256) {
    int i = e >> 7, c = e & 127;
    Wl[i][c] = W[((size_t)((c >> 4) * 128 + i)) * 16 + (c & 15)];
  }
  const int r  = tid >> 5;
  const int cg = (tid & 31) << 2;
  const size_t rb = (size_t)xb * 64;
  const float SCALE_Q = 0.25f * 1.4426950408889634f;   // norm * log2(e)
  for (int pass = 0; pass < 8; ++pass) {
    __syncthreads();
    size_t row0 = rb + pass * 8;
    for (int e = tid; e < 8 * 128; e += 256)
      inl[e >> 7][e & 127] = in[(row0 + (e >> 7)) * 128 + (e & 127)];
    __syncthreads();
    f32x4 acc = {0.f, 0.f, 0.f, 0.f};
    #pragma unroll 8
    for (int i = 0; i < 128; ++i) {
      float a = inl[r][i];
      acc += a * *(const f32x4*)&Wl[i][cg];
    }
    size_t grow = row0 + r;
    if (mat == 0) {
      uint2v o = { pkbf(acc[0] * SCALE_Q, acc[1] * SCALE_Q),
                   pkbf(acc[2] * SCALE_Q, acc[3] * SCALE_Q) };
      *(uint2v*)(Qp + grow * DIM + cg) = o;
    } else if (mat == 1) {
      uint2v o = { pkbf(acc[0], acc[1]), pkbf(acc[2], acc[3]) };
      *(uint2v*)(Kp + grow * DIM + cg) = o;
    } else {
      size_t b = grow >> 12, n = grow & 4095;
      #pragma unroll
      for (int j = 0; j < 4; ++j) {
        const int c = cg + j;
        Vt32[((size_t)(b * 8 + (c >> 4)) * 32 + (c & 15)) * SEQ + n] =
            f2bf(acc[j]);
      }
    }
  }
}

// ---------------- kernel 2: fused flash attention, split-K -----------------
// 256-thread blocks (4 waves; finer CU packing than 512), grid = 512*NS.
// Wave = head 4*(blockIdx&1)+wv; no LDS, no barriers, raw p=exp2(s).
// V channel clamp: lane reads channel min(q,16); ch16=ones -> lsum in oacc[8].
__global__ __launch_bounds__(256, 8) void k_flash(
    const unsigned short* __restrict__ Qp, const unsigned short* __restrict__ Kp,
    const unsigned short* __restrict__ Vt32, const unsigned* __restrict__ bits,
    float* __restrict__ parts, float* __restrict__ Lb, int NT) {
  const int tid  = threadIdx.x;
  const int wv   = tid >> 6;           // 0..3
  const int lane = tid & 63;
  const int q    = lane & 31;
  const int hi   = lane >> 5;
  const int h    = ((blockIdx.x & 1) << 2) + wv;
  const int bqb  = (blockIdx.x >> 1) & 255;
  const int b    = bqb >> 7;
  const int qb   = (bqb & 127) << 5;
  const int sp   = blockIdx.x >> 9;
  const int kt0  = sp * NT;

  const bf16x8 qfrag =
      *(const bf16x8*)(Qp + ((size_t)b * SEQ + qb + q) * DIM + h * HDK + hi * 8);
  const unsigned short* kbase =
      Kp + ((size_t)b * SEQ) * DIM + h * HDK + hi * 8 + (size_t)q * DIM;
  const int qv = q < 16 ? q : 16;      // clamp: q>=16 -> ones channel
  const unsigned short* vbase =
      Vt32 + ((size_t)(b * 8 + h) * 32 + qv) * SEQ + hi * 8;
  const unsigned* bq = bits + ((size_t)b * 128 + kt0) * SEQ + qb + q;

  int koff = (kt0 << 5) * DIM;
  int boff = 0;
  int voff = kt0 << 5;

  unsigned mr0 = bq[0], mr1 = bq[SEQ];
  bf16x8 kf0 = *(const bf16x8*)(kbase + koff);
  bf16x8 kf1 = *(const bf16x8*)(kbase + koff + 32 * DIM);

  f32x16 oacc = {};                    // O^T: row=channel crow(r,hi), col=q
  const int niter = NT >> 1;

  for (int t = 0; t < niter; ++t) {
    f32x16 z16 = {};
    f32x16 st0 = __builtin_amdgcn_mfma_f32_32x32x16_bf16(kf0, qfrag, z16, 0, 0, 0);
    f32x16 st1 = __builtin_amdgcn_mfma_f32_32x32x16_bf16(kf1, qfrag, z16, 0, 0, 0);

    // prefetch next pair (mask bits + K)
    const int adv = (t + 1 < niter) ? 1 : 0;
    const unsigned mrn0 = bq[boff + adv * 2 * SEQ];
    const unsigned mrn1 = bq[boff + adv * 2 * SEQ + SEQ];
    const bf16x8 kfn0 = *(const bf16x8*)(kbase + koff + adv * 64 * DIM);
    const bf16x8 kfn1 = *(const bf16x8*)(kbase + koff + adv * 64 * DIM + 32 * DIM);

    const unsigned mrs0 = mr0 >> (hi << 2);
    const unsigned mrs1 = mr1 >> (hi << 2);

    #pragma unroll
    for (int T = 0; T < 2; ++T) {
      const unsigned mrs = T ? mrs1 : mrs0;
      #pragma unroll
      for (int sl = 0; sl < 2; ++sl) {
        float pe[8];
        #pragma unroll
        for (int j = 0; j < 8; ++j) {
          const int r = sl * 8 + j;
          const int kvc = (r & 3) + 8 * (r >> 2);    // + 4*hi via mrs shift
          pe[j] = apply_keep(fexp2(T ? st1[r] : st0[r]), mrs, kvc);
        }
        const unsigned a0 = pkbf_fast(pe[0], pe[1]);
        const unsigned a1 = pkbf_fast(pe[2], pe[3]);
        const unsigned b0 = pkbf_fast(pe[4], pe[5]);
        const unsigned b1 = pkbf_fast(pe[6], pe[7]);
        const uint2v s0 = __builtin_amdgcn_permlane32_swap(a0, b0, false, false);
        const uint2v s1 = __builtin_amdgcn_permlane32_swap(a1, b1, false, false);
        const uint4v w = { s0.x, s1.x, s0.y, s1.y };
        const bf16x8 pfrag = __builtin_bit_cast(bf16x8, w);
        const bf16x8 vf = *(const bf16x8*)(vbase + voff + T * 32 + sl * 16);
        oacc = __builtin_amdgcn_mfma_f32_32x32x16_bf16(vf, pfrag, oacc, 0, 0, 0);
      }
    }
    kf0 = kfn0; kf1 = kfn1; mr0 = mrn0; mr1 = mrn1;
    koff += adv * 64 * DIM;
    boff += adv * 2 * SEQ;
    voff += 64;
  }

  // ---- epilogue: unnormalized partials (channels 0..15) + lsum (ch 16)
  const size_t row = (size_t)b * SEQ + qb + q;
  float* hp = parts + ((size_t)sp * 2 * SEQ + row) * DIM + h * HDK;
  f32x4 w0 = { oacc[0], oacc[1], oacc[2], oacc[3] };
  f32x4 w1 = { oacc[4], oacc[5], oacc[6], oacc[7] };
  *(f32x4*)(hp + 4 * hi)     = w0;
  *(f32x4*)(hp + 8 + 4 * hi) = w1;
  if (hi == 0)
    Lb[((size_t)sp * 2 * SEQ + row) * NHEADS + h] = oacc[8];
}

// ---------------- kernel 3: combine + output projection (fused) ------------
__global__ __launch_bounds__(256) void k_oproj(
    const float* __restrict__ parts, const float* __restrict__ Lb,
    const float* __restrict__ Wo, float* __restrict__ out, int NS) {
  __shared__ float Wl[128][128];
  __shared__ float inl[8][128];
  for (int e = threadIdx.x; e < 128 * 128; e += 256) Wl[e >> 7][e & 127] = Wo[e];
  const int r  = threadIdx.x >> 5;
  const int cg = (threadIdx.x & 31) << 2;
  const int h  = cg >> 4;
  const size_t R  = (size_t)2 * SEQ;
  const size_t rb = (size_t)blockIdx.x * 32;
  for (int pass = 0; pass < 4; ++pass) {
    __syncthreads();
    const size_t row = rb + pass * 8 + r;
    float l = 0.f;
    f32x4 acc = {0.f, 0.f, 0.f, 0.f};
    for (int sp = 0; sp < NS; ++sp) {
      l += Lb[(sp * R + row) * NHEADS + h];
      acc += *(const f32x4*)&parts[(sp * R + row) * DIM + cg];
    }
    const float rinv = l > 0.f ? 1.0f / l : 0.f;
    *(f32x4*)&inl[r][cg] = acc * rinv;
    __syncthreads();
    f32x4 o = {0.f, 0.f, 0.f, 0.f};
    #pragma unroll 8
    for (int i = 0; i < 128; ++i) o += inl[r][i] * *(const f32x4*)&Wl[i][cg];
    *(f32x4*)(out + row * 128 + cg) = o;
  }
}

// ---------------- launch ---------------------------------------------------
extern "C" void kernel_launch(void* const* d_in, const int* in_sizes, int n_in,
                              void* d_out, int out_size, void* d_ws, size_t ws_size,
                              hipStream_t stream) {
  const float* qin = (const float*)d_in[0];
  const float* hin = (const float*)d_in[1];
  const void* mask = d_in[2];
  const float* Wq  = (const float*)d_in[3];
  const float* Wk  = (const float*)d_in[4];
  const float* Wv  = (const float*)d_in[5];
  const float* Wo  = (const float*)d_in[6];
  float* out = (float*)d_out;
  char* ws = (char*)d_ws;

  const size_t MAT   = (size_t)2 * SEQ * DIM;    // elems per bf16 matrix
  const size_t VMAT  = (size_t)16 * 32 * SEQ;    // Vt32 elems (4MB)
  const size_t R     = (size_t)2 * SEQ;
  const size_t BITS  = (size_t)2 * 128 * SEQ;

  int NS = 4;
  while (NS > 1) {
    size_t need = 2 * MAT * 2 + VMAT * 2 + BITS * 4 +
                  (size_t)NS * (R * DIM * 4 + R * NHEADS * 4);
    if (need <= ws_size) break;
    NS >>= 1;
  }
  const int NT = 128 / NS;

  unsigned short* Qp    = (unsigned short*)ws;
  unsigned short* Kp    = Qp + MAT;
  unsigned short* Vt32  = Kp + MAT;                    // 4 MB
  unsigned*       bits  = (unsigned*)(Vt32 + VMAT);    // 4 MB
  float*          parts = (float*)(bits + BITS);       // NS * 4 MB
  float*          Lb    = parts + (size_t)NS * R * DIM;

  k_pre<<<900, 256, 0, stream>>>(qin, hin, Wq, Wk, Wv, mask, Qp, Kp, Vt32, bits);
  k_flash<<<512 * NS, 256, 0, stream>>>(Qp, Kp, Vt32, bits, parts, Lb, NT);
  k_oproj<<<256, 256, 0, stream>>>(parts, Lb, Wo, out, NS);
}

// Round 12
// 136.689 us; speedup vs baseline: 1.2652x; 1.2652x over previous
//
#include <hip/hip_runtime.h>
#include <stdint.h>

#define SEQ 4096
#define DIM 128
#define NHEADS 8
#define HDK 16

typedef __bf16 bf16x2 __attribute__((ext_vector_type(2)));
typedef __bf16 bf16x8 __attribute__((ext_vector_type(8)));
typedef float f32x16 __attribute__((ext_vector_type(16)));
typedef float f32x4 __attribute__((ext_vector_type(4)));
typedef unsigned uint2v __attribute__((ext_vector_type(2)));
typedef unsigned uint4v __attribute__((ext_vector_type(4)));

__device__ inline unsigned short f2bf(float x) {
  unsigned u = __builtin_bit_cast(unsigned, x);
  u = (u + 0x7FFFu + ((u >> 16) & 1u)) >> 16;
  return (unsigned short)u;
}
__device__ inline unsigned pkbf(float lo, float hi) {
  return (unsigned)f2bf(lo) | ((unsigned)f2bf(hi) << 16);
}
// native RNE casts; compiler fuses pairs into v_cvt_pk_bf16_f32
__device__ inline unsigned pkbf_fast(float lo, float hi) {
  bf16x2 t;
  t[0] = (__bf16)lo;
  t[1] = (__bf16)hi;
  return __builtin_bit_cast(unsigned, t);
}
__device__ inline float fexp2(float x) {
#if __has_builtin(__builtin_amdgcn_exp2f)
  return __builtin_amdgcn_exp2f(x);
#else
  return exp2f(x);
#endif
}
// e if bit kvc of mrs clear, else 0  (sbfe + andn)
__device__ inline float apply_keep(float e, unsigned mrs, int kvc) {
#if __has_builtin(__builtin_amdgcn_sbfe)
  const unsigned m = (unsigned)__builtin_amdgcn_sbfe((int)mrs, kvc, 1);
#else
  const unsigned m = (unsigned)(((int)(mrs << (31 - kvc))) >> 31);
#endif
  return __builtin_bit_cast(float, __builtin_bit_cast(unsigned, e) & ~m);
}

// ---------------- kernel 0: fused pre-processing ---------------------------
// One dispatch, three block roles (overlap VALU-heavy proj with the HBM-heavy
// mask stream):
//   blocks   0..383 : projections (mat = bid>>7: Qp scaled / Kp / Vt32 ch<16)
//   blocks 384..895 : mask -> packed bits transpose (thread-owns-word)
//   blocks 896..899 : Vt32 channel-16 init = 1.0 (lsum row)
__global__ __launch_bounds__(256) void k_pre(
    const float* __restrict__ qin, const float* __restrict__ hin,
    const float* __restrict__ Wq, const float* __restrict__ Wk,
    const float* __restrict__ Wv, const void* __restrict__ maskp,
    unsigned short* __restrict__ Qp, unsigned short* __restrict__ Kp,
    unsigned short* __restrict__ Vt32, unsigned* __restrict__ bits) {
  __shared__ float Wl[128][128];
  __shared__ float inl[8][128];
  const int bid = (int)blockIdx.x;
  const int tid = threadIdx.x;

  if (bid >= 896) {                    // ---- Vt32 ones-row init
    unsigned* Vt32w = (unsigned*)Vt32;
    const int base = (bid - 896) * 256 + tid;     // 0..1023
    #pragma unroll
    for (int j = 0; j < 32; ++j) {
      const int w = base + j * 1024;
      const int bh = w >> 11, n2 = w & 2047;
      Vt32w[((size_t)bh * 32 + 16) * 2048 + n2] = 0x3F803F80u;  // bf16 {1,1}
    }
    return;
  }

  if (bid >= 384) {                    // ---- mask transpose (ILP, no ballots)
    unsigned (*mlds)[17] = (unsigned (*)[17])Wl;  // 8.7KB overlay on Wl
    const unsigned*      mw = (const unsigned*)maskp;
    const unsigned char* m8 = (const unsigned char*)maskp;
    bool wordmode = true;
    #pragma unroll
    for (int i = 0; i < 32; ++i) {
      unsigned w = mw[i];
      if (!(w == 0u || w == 1u || w == 0x3F800000u)) wordmode = false;
    }
    const int mb = bid - 384;                      // 0..511
    const int b = mb >> 8;
    const int rowbase = (mb & 255) * 16;
    const int kt = tid & 127;
    #pragma unroll
    for (int p = 0; p < 8; ++p) {
      const int rl = p * 2 + (tid >> 7);           // 0..15
      const size_t g = ((size_t)b * SEQ + rowbase + rl) * SEQ + kt * 32;
      unsigned word = 0;
      if (wordmode) {
        uint4v w0 = *(const uint4v*)(mw + g);
        uint4v w1 = *(const uint4v*)(mw + g + 4);
        uint4v w2 = *(const uint4v*)(mw + g + 8);
        uint4v w3 = *(const uint4v*)(mw + g + 12);
        uint4v w4 = *(const uint4v*)(mw + g + 16);
        uint4v w5 = *(const uint4v*)(mw + g + 20);
        uint4v w6 = *(const uint4v*)(mw + g + 24);
        uint4v w7 = *(const uint4v*)(mw + g + 28);
        const uint4v wv[8] = { w0, w1, w2, w3, w4, w5, w6, w7 };
        #pragma unroll
        for (int j = 0; j < 8; ++j)
          #pragma unroll
          for (int e = 0; e < 4; ++e) {
            const unsigned w = wv[j][e];
            word |= ((w | (0u - w)) >> 31) << (4 * j + e);   // (w!=0)
          }
      } else {
        uint4v c0 = *(const uint4v*)(m8 + g);
        uint4v c1 = *(const uint4v*)(m8 + g + 16);
        const uint4v cv[2] = { c0, c1 };
        #pragma unroll
        for (int j = 0; j < 2; ++j)
          #pragma unroll
          for (int e = 0; e < 4; ++e) {
            unsigned w = cv[j][e];
            #pragma unroll
            for (int by = 0; by < 4; ++by) {
              word |= ((w & 0xFFu) ? 1u : 0u) << (16 * j + 4 * e + by);
              w >>= 8;
            }
          }
      }
      mlds[kt][rl] = word;
    }
    __syncthreads();
    #pragma unroll
    for (int j = 0; j < 8; ++j) {
      const int idx = tid + 256 * j;
      const int k2 = idx >> 4, rl = idx & 15;
      bits[((size_t)b * 128 + k2) * SEQ + rowbase + rl] = mlds[k2][rl];
    }
    return;
  }

  // ---- projections: Qp[b][n][h*16+k] (scaled), Kp[...], Vt32[b*8+h][v][n]
  const int mat = bid >> 7;            // 0,1,2
  const int xb  = bid & 127;
  const float* in = (mat == 0) ? qin : hin;
  const float* W  = (mat == 0) ? Wq : (mat == 1 ? Wk : Wv);
  for (int e = tid; e < 128 * 128; e += 256) {
    int i = e >> 7, c = e & 127;
    Wl[i][c] = W[((size_t)((c >> 4) * 128 + i)) * 16 + (c & 15)];
  }
  const int r  = tid >> 5;
  const int cg = (tid & 31) << 2;
  const size_t rb = (size_t)xb * 64;
  const float SCALE_Q = 0.25f * 1.4426950408889634f;   // norm * log2(e)
  for (int pass = 0; pass < 8; ++pass) {
    __syncthreads();
    size_t row0 = rb + pass * 8;
    for (int e = tid; e < 8 * 128; e += 256)
      inl[e >> 7][e & 127] = in[(row0 + (e >> 7)) * 128 + (e & 127)];
    __syncthreads();
    f32x4 acc = {0.f, 0.f, 0.f, 0.f};
    #pragma unroll 8
    for (int i = 0; i < 128; ++i) {
      float a = inl[r][i];
      acc += a * *(const f32x4*)&Wl[i][cg];
    }
    size_t grow = row0 + r;
    if (mat == 0) {
      uint2v o = { pkbf(acc[0] * SCALE_Q, acc[1] * SCALE_Q),
                   pkbf(acc[2] * SCALE_Q, acc[3] * SCALE_Q) };
      *(uint2v*)(Qp + grow * DIM + cg) = o;
    } else if (mat == 1) {
      uint2v o = { pkbf(acc[0], acc[1]), pkbf(acc[2], acc[3]) };
      *(uint2v*)(Kp + grow * DIM + cg) = o;
    } else {
      size_t b = grow >> 12, n = grow & 4095;
      #pragma unroll
      for (int j = 0; j < 4; ++j) {
        const int c = cg + j;
        Vt32[((size_t)(b * 8 + (c >> 4)) * 32 + (c & 15)) * SEQ + n] =
            f2bf(acc[j]);
      }
    }
  }
}

// ---------------- kernel 2: fused flash attention, split-K -----------------
// r10-proven config: 512 threads, __launch_bounds__(512,4) = 128-VGPR cap
// (uses 44, NO spill).  r11's (256,8) forced a 64-cap -> spill -> +50%.
// grid = 256*NS; 8 independent waves/block, no LDS, no barriers.
// Raw p=exp2(s); V channel clamp min(q,16); lsum via ones-channel in oacc[8].
__global__ __launch_bounds__(512, 4) void k_flash(
    const unsigned short* __restrict__ Qp, const unsigned short* __restrict__ Kp,
    const unsigned short* __restrict__ Vt32, const unsigned* __restrict__ bits,
    float* __restrict__ parts, float* __restrict__ Lb, int NT) {
  const int tid  = threadIdx.x;
  const int wv   = tid >> 6;
  const int lane = tid & 63;
  const int q    = lane & 31;
  const int hi   = lane >> 5;
  const int h    = wv;
  const int sp   = blockIdx.x >> 8;
  const int bqb  = blockIdx.x & 255;
  const int b    = bqb >> 7;
  const int qb   = (bqb & 127) << 5;
  const int kt0  = sp * NT;

  const bf16x8 qfrag =
      *(const bf16x8*)(Qp + ((size_t)b * SEQ + qb + q) * DIM + h * HDK + hi * 8);
  const unsigned short* kbase =
      Kp + ((size_t)b * SEQ) * DIM + h * HDK + hi * 8 + (size_t)q * DIM;
  const int qv = q < 16 ? q : 16;      // clamp: q>=16 -> ones channel
  const unsigned short* vbase =
      Vt32 + ((size_t)(b * 8 + h) * 32 + qv) * SEQ + hi * 8;
  const unsigned* bq = bits + ((size_t)b * 128 + kt0) * SEQ + qb + q;

  int koff = (kt0 << 5) * DIM;
  int boff = 0;
  int voff = kt0 << 5;

  unsigned mr0 = bq[0], mr1 = bq[SEQ];
  bf16x8 kf0 = *(const bf16x8*)(kbase + koff);
  bf16x8 kf1 = *(const bf16x8*)(kbase + koff + 32 * DIM);

  f32x16 oacc = {};                    // O^T: row=channel crow(r,hi), col=q
  const int niter = NT >> 1;

  for (int t = 0; t < niter; ++t) {
    f32x16 z16 = {};
    f32x16 st0 = __builtin_amdgcn_mfma_f32_32x32x16_bf16(kf0, qfrag, z16, 0, 0, 0);
    f32x16 st1 = __builtin_amdgcn_mfma_f32_32x32x16_bf16(kf1, qfrag, z16, 0, 0, 0);

    // prefetch next pair (mask bits + K)
    const int adv = (t + 1 < niter) ? 1 : 0;
    const unsigned mrn0 = bq[boff + adv * 2 * SEQ];
    const unsigned mrn1 = bq[boff + adv * 2 * SEQ + SEQ];
    const bf16x8 kfn0 = *(const bf16x8*)(kbase + koff + adv * 64 * DIM);
    const bf16x8 kfn1 = *(const bf16x8*)(kbase + koff + adv * 64 * DIM + 32 * DIM);

    const unsigned mrs0 = mr0 >> (hi << 2);
    const unsigned mrs1 = mr1 >> (hi << 2);

    #pragma unroll
    for (int T = 0; T < 2; ++T) {
      const unsigned mrs = T ? mrs1 : mrs0;
      #pragma unroll
      for (int sl = 0; sl < 2; ++sl) {
        float pe[8];
        #pragma unroll
        for (int j = 0; j < 8; ++j) {
          const int r = sl * 8 + j;
          const int kvc = (r & 3) + 8 * (r >> 2);    // + 4*hi via mrs shift
          pe[j] = apply_keep(fexp2(T ? st1[r] : st0[r]), mrs, kvc);
        }
        const unsigned a0 = pkbf_fast(pe[0], pe[1]);
        const unsigned a1 = pkbf_fast(pe[2], pe[3]);
        const unsigned b0 = pkbf_fast(pe[4], pe[5]);
        const unsigned b1 = pkbf_fast(pe[6], pe[7]);
        const uint2v s0 = __builtin_amdgcn_permlane32_swap(a0, b0, false, false);
        const uint2v s1 = __builtin_amdgcn_permlane32_swap(a1, b1, false, false);
        const uint4v w = { s0.x, s1.x, s0.y, s1.y };
        const bf16x8 pfrag = __builtin_bit_cast(bf16x8, w);
        const bf16x8 vf = *(const bf16x8*)(vbase + voff + T * 32 + sl * 16);
        oacc = __builtin_amdgcn_mfma_f32_32x32x16_bf16(vf, pfrag, oacc, 0, 0, 0);
      }
    }
    kf0 = kfn0; kf1 = kfn1; mr0 = mrn0; mr1 = mrn1;
    koff += adv * 64 * DIM;
    boff += adv * 2 * SEQ;
    voff += 64;
  }

  // ---- epilogue: unnormalized partials (channels 0..15) + lsum (ch 16)
  const size_t row = (size_t)b * SEQ + qb + q;
  float* hp = parts + ((size_t)sp * 2 * SEQ + row) * DIM + h * HDK;
  f32x4 w0 = { oacc[0], oacc[1], oacc[2], oacc[3] };
  f32x4 w1 = { oacc[4], oacc[5], oacc[6], oacc[7] };
  *(f32x4*)(hp + 4 * hi)     = w0;
  *(f32x4*)(hp + 8 + 4 * hi) = w1;
  if (hi == 0)
    Lb[((size_t)sp * 2 * SEQ + row) * NHEADS + h] = oacc[8];
}

// ---------------- kernel 3: combine + output projection (fused) ------------
__global__ __launch_bounds__(256) void k_oproj(
    const float* __restrict__ parts, const float* __restrict__ Lb,
    const float* __restrict__ Wo, float* __restrict__ out, int NS) {
  __shared__ float Wl[128][128];
  __shared__ float inl[8][128];
  for (int e = threadIdx.x; e < 128 * 128; e += 256) Wl[e >> 7][e & 127] = Wo[e];
  const int r  = threadIdx.x >> 5;
  const int cg = (threadIdx.x & 31) << 2;
  const int h  = cg >> 4;
  const size_t R  = (size_t)2 * SEQ;
  const size_t rb = (size_t)blockIdx.x * 32;
  for (int pass = 0; pass < 4; ++pass) {
    __syncthreads();
    const size_t row = rb + pass * 8 + r;
    float l = 0.f;
    f32x4 acc = {0.f, 0.f, 0.f, 0.f};
    for (int sp = 0; sp < NS; ++sp) {
      l += Lb[(sp * R + row) * NHEADS + h];
      acc += *(const f32x4*)&parts[(sp * R + row) * DIM + cg];
    }
    const float rinv = l > 0.f ? 1.0f / l : 0.f;
    *(f32x4*)&inl[r][cg] = acc * rinv;
    __syncthreads();
    f32x4 o = {0.f, 0.f, 0.f, 0.f};
    #pragma unroll 8
    for (int i = 0; i < 128; ++i) o += inl[r][i] * *(const f32x4*)&Wl[i][cg];
    *(f32x4*)(out + row * 128 + cg) = o;
  }
}

// ---------------- launch ---------------------------------------------------
extern "C" void kernel_launch(void* const* d_in, const int* in_sizes, int n_in,
                              void* d_out, int out_size, void* d_ws, size_t ws_size,
                              hipStream_t stream) {
  const float* qin = (const float*)d_in[0];
  const float* hin = (const float*)d_in[1];
  const void* mask = d_in[2];
  const float* Wq  = (const float*)d_in[3];
  const float* Wk  = (const float*)d_in[4];
  const float* Wv  = (const float*)d_in[5];
  const float* Wo  = (const float*)d_in[6];
  float* out = (float*)d_out;
  char* ws = (char*)d_ws;

  const size_t MAT   = (size_t)2 * SEQ * DIM;    // elems per bf16 matrix
  const size_t VMAT  = (size_t)16 * 32 * SEQ;    // Vt32 elems (4MB)
  const size_t R     = (size_t)2 * SEQ;
  const size_t BITS  = (size_t)2 * 128 * SEQ;

  int NS = 4;
  while (NS > 1) {
    size_t need = 2 * MAT * 2 + VMAT * 2 + BITS * 4 +
                  (size_t)NS * (R * DIM * 4 + R * NHEADS * 4);
    if (need <= ws_size) break;
    NS >>= 1;
  }
  const int NT = 128 / NS;

  unsigned short* Qp    = (unsigned short*)ws;
  unsigned short* Kp    = Qp + MAT;
  unsigned short* Vt32  = Kp + MAT;                    // 4 MB
  unsigned*       bits  = (unsigned*)(Vt32 + VMAT);    // 4 MB
  float*          parts = (float*)(bits + BITS);       // NS * 4 MB
  float*          Lb    = parts + (size_t)NS * R * DIM;

  k_pre<<<900, 256, 0, stream>>>(qin, hin, Wq, Wk, Wv, mask, Qp, Kp, Vt32, bits);
  k_flash<<<256 * NS, 512, 0, stream>>>(Qp, Kp, Vt32, bits, parts, Lb, NT);
  k_oproj<<<256, 256, 0, stream>>>(parts, Lb, Wo, out, NS);
}

// Round 13
// 130.326 us; speedup vs baseline: 1.3270x; 1.0488x over previous
//
#include <hip/hip_runtime.h>
#include <stdint.h>

#define SEQ 4096
#define DIM 128
#define NHEADS 8
#define HDK 16

typedef __bf16 bf16x2 __attribute__((ext_vector_type(2)));
typedef __bf16 bf16x8 __attribute__((ext_vector_type(8)));
typedef float f32x16 __attribute__((ext_vector_type(16)));
typedef float f32x4 __attribute__((ext_vector_type(4)));
typedef unsigned uint2v __attribute__((ext_vector_type(2)));
typedef unsigned uint4v __attribute__((ext_vector_type(4)));

__device__ inline unsigned short f2bf(float x) {
  unsigned u = __builtin_bit_cast(unsigned, x);
  u = (u + 0x7FFFu + ((u >> 16) & 1u)) >> 16;
  return (unsigned short)u;
}
__device__ inline unsigned pkbf(float lo, float hi) {
  return (unsigned)f2bf(lo) | ((unsigned)f2bf(hi) << 16);
}
// native RNE casts; compiler fuses pairs into v_cvt_pk_bf16_f32
__device__ inline unsigned pkbf_fast(float lo, float hi) {
  bf16x2 t;
  t[0] = (__bf16)lo;
  t[1] = (__bf16)hi;
  return __builtin_bit_cast(unsigned, t);
}
__device__ inline float fexp2(float x) {
#if __has_builtin(__builtin_amdgcn_exp2f)
  return __builtin_amdgcn_exp2f(x);
#else
  return exp2f(x);
#endif
}
// e if bit kvc of PRE-INVERTED mask mrsi is set (keep), else 0: sbfe + and
// (mrsi inverted once per tile -> no per-element v_not)
__device__ inline float keep_and(float e, unsigned mrsi, int kvc) {
#if __has_builtin(__builtin_amdgcn_sbfe)
  const unsigned m = (unsigned)__builtin_amdgcn_sbfe((int)mrsi, kvc, 1);
#else
  const unsigned m = (unsigned)(((int)(mrsi << (31 - kvc))) >> 31);
#endif
  return __builtin_bit_cast(float, __builtin_bit_cast(unsigned, e) & m);
}

// ---------------- kernel 0: fused pre-processing ---------------------------
// One dispatch, three block roles (overlap VALU-heavy proj with the HBM-heavy
// mask stream):
//   blocks   0..383 : projections (mat = bid>>7: Qp scaled / Kp / Vt32 ch<16)
//   blocks 384..895 : mask -> packed bits transpose (thread-owns-word)
//   blocks 896..899 : Vt32 channel-16 init = 1.0 (lsum row)
__global__ __launch_bounds__(256) void k_pre(
    const float* __restrict__ qin, const float* __restrict__ hin,
    const float* __restrict__ Wq, const float* __restrict__ Wk,
    const float* __restrict__ Wv, const void* __restrict__ maskp,
    unsigned short* __restrict__ Qp, unsigned short* __restrict__ Kp,
    unsigned short* __restrict__ Vt32, unsigned* __restrict__ bits) {
  __shared__ float Wl[128][128];
  __shared__ float inl[8][128];
  const int bid = (int)blockIdx.x;
  const int tid = threadIdx.x;

  if (bid >= 896) {                    // ---- Vt32 ones-row init
    unsigned* Vt32w = (unsigned*)Vt32;
    const int base = (bid - 896) * 256 + tid;     // 0..1023
    #pragma unroll
    for (int j = 0; j < 32; ++j) {
      const int w = base + j * 1024;
      const int bh = w >> 11, n2 = w & 2047;
      Vt32w[((size_t)bh * 32 + 16) * 2048 + n2] = 0x3F803F80u;  // bf16 {1,1}
    }
    return;
  }

  if (bid >= 384) {                    // ---- mask transpose (ILP, no ballots)
    unsigned (*mlds)[17] = (unsigned (*)[17])Wl;  // 8.7KB overlay on Wl
    const unsigned*      mw = (const unsigned*)maskp;
    const unsigned char* m8 = (const unsigned char*)maskp;
    bool wordmode = true;
    #pragma unroll
    for (int i = 0; i < 32; ++i) {
      unsigned w = mw[i];
      if (!(w == 0u || w == 1u || w == 0x3F800000u)) wordmode = false;
    }
    const int mb = bid - 384;                      // 0..511
    const int b = mb >> 8;
    const int rowbase = (mb & 255) * 16;
    const int kt = tid & 127;
    #pragma unroll
    for (int p = 0; p < 8; ++p) {
      const int rl = p * 2 + (tid >> 7);           // 0..15
      const size_t g = ((size_t)b * SEQ + rowbase + rl) * SEQ + kt * 32;
      unsigned word = 0;
      if (wordmode) {
        uint4v w0 = *(const uint4v*)(mw + g);
        uint4v w1 = *(const uint4v*)(mw + g + 4);
        uint4v w2 = *(const uint4v*)(mw + g + 8);
        uint4v w3 = *(const uint4v*)(mw + g + 12);
        uint4v w4 = *(const uint4v*)(mw + g + 16);
        uint4v w5 = *(const uint4v*)(mw + g + 20);
        uint4v w6 = *(const uint4v*)(mw + g + 24);
        uint4v w7 = *(const uint4v*)(mw + g + 28);
        const uint4v wv[8] = { w0, w1, w2, w3, w4, w5, w6, w7 };
        #pragma unroll
        for (int j = 0; j < 8; ++j)
          #pragma unroll
          for (int e = 0; e < 4; ++e) {
            const unsigned w = wv[j][e];
            word |= ((w | (0u - w)) >> 31) << (4 * j + e);   // (w!=0)
          }
      } else {
        uint4v c0 = *(const uint4v*)(m8 + g);
        uint4v c1 = *(const uint4v*)(m8 + g + 16);
        const uint4v cv[2] = { c0, c1 };
        #pragma unroll
        for (int j = 0; j < 2; ++j)
          #pragma unroll
          for (int e = 0; e < 4; ++e) {
            unsigned w = cv[j][e];
            #pragma unroll
            for (int by = 0; by < 4; ++by) {
              word |= ((w & 0xFFu) ? 1u : 0u) << (16 * j + 4 * e + by);
              w >>= 8;
            }
          }
      }
      mlds[kt][rl] = word;
    }
    __syncthreads();
    #pragma unroll
    for (int j = 0; j < 8; ++j) {
      const int idx = tid + 256 * j;
      const int k2 = idx >> 4, rl = idx & 15;
      bits[((size_t)b * 128 + k2) * SEQ + rowbase + rl] = mlds[k2][rl];
    }
    return;
  }

  // ---- projections: Qp[b][n][h*16+k] (scaled), Kp[...], Vt32[b*8+h][v][n]
  const int mat = bid >> 7;            // 0,1,2
  const int xb  = bid & 127;
  const float* in = (mat == 0) ? qin : hin;
  const float* W  = (mat == 0) ? Wq : (mat == 1 ? Wk : Wv);
  for (int e = tid; e < 128 * 128; e += 256) {
    int i = e >> 7, c = e & 127;
    Wl[i][c] = W[((size_t)((c >> 4) * 128 + i)) * 16 + (c & 15)];
  }
  const int r  = tid >> 5;
  const int cg = (tid & 31) << 2;
  const size_t rb = (size_t)xb * 64;
  const float SCALE_Q = 0.25f * 1.4426950408889634f;   // norm * log2(e)
  for (int pass = 0; pass < 8; ++pass) {
    __syncthreads();
    size_t row0 = rb + pass * 8;
    for (int e = tid; e < 8 * 128; e += 256)
      inl[e >> 7][e & 127] = in[(row0 + (e >> 7)) * 128 + (e & 127)];
    __syncthreads();
    f32x4 acc = {0.f, 0.f, 0.f, 0.f};
    #pragma unroll 8
    for (int i = 0; i < 128; ++i) {
      float a = inl[r][i];
      acc += a * *(const f32x4*)&Wl[i][cg];
    }
    size_t grow = row0 + r;
    if (mat == 0) {
      uint2v o = { pkbf(acc[0] * SCALE_Q, acc[1] * SCALE_Q),
                   pkbf(acc[2] * SCALE_Q, acc[3] * SCALE_Q) };
      *(uint2v*)(Qp + grow * DIM + cg) = o;
    } else if (mat == 1) {
      uint2v o = { pkbf(acc[0], acc[1]), pkbf(acc[2], acc[3]) };
      *(uint2v*)(Kp + grow * DIM + cg) = o;
    } else {
      size_t b = grow >> 12, n = grow & 4095;
      #pragma unroll
      for (int j = 0; j < 4; ++j) {
        const int c = cg + j;
        Vt32[((size_t)(b * 8 + (c >> 4)) * 32 + (c & 15)) * SEQ + n] =
            f2bf(acc[j]);
      }
    }
  }
}

// ---------------- kernel 2: fused flash attention, split-K -----------------
// r10 config (512 thr, (512,4): 128-VGPR cap, ~60-76 used, no spill) plus:
//  - V prefetched one iteration ahead (K/bits already were) -> L2 latency off
//    the critical path
//  - mask pre-inverted per tile -> keep_and is sbfe+and (no per-elem v_not)
__global__ __launch_bounds__(512, 4) void k_flash(
    const unsigned short* __restrict__ Qp, const unsigned short* __restrict__ Kp,
    const unsigned short* __restrict__ Vt32, const unsigned* __restrict__ bits,
    float* __restrict__ parts, float* __restrict__ Lb, int NT) {
  const int tid  = threadIdx.x;
  const int wv   = tid >> 6;
  const int lane = tid & 63;
  const int q    = lane & 31;
  const int hi   = lane >> 5;
  const int h    = wv;
  const int sp   = blockIdx.x >> 8;
  const int bqb  = blockIdx.x & 255;
  const int b    = bqb >> 7;
  const int qb   = (bqb & 127) << 5;
  const int kt0  = sp * NT;

  const bf16x8 qfrag =
      *(const bf16x8*)(Qp + ((size_t)b * SEQ + qb + q) * DIM + h * HDK + hi * 8);
  const unsigned short* kbase =
      Kp + ((size_t)b * SEQ) * DIM + h * HDK + hi * 8 + (size_t)q * DIM;
  const int qv = q < 16 ? q : 16;      // clamp: q>=16 -> ones channel
  const unsigned short* vbase =
      Vt32 + ((size_t)(b * 8 + h) * 32 + qv) * SEQ + hi * 8;
  const unsigned* bq = bits + ((size_t)b * 128 + kt0) * SEQ + qb + q;

  int koff = (kt0 << 5) * DIM;
  int boff = 0;
  int voff = kt0 << 5;

  unsigned mr0 = bq[0], mr1 = bq[SEQ];
  bf16x8 kf0 = *(const bf16x8*)(kbase + koff);
  bf16x8 kf1 = *(const bf16x8*)(kbase + koff + 32 * DIM);
  bf16x8 vf0 = *(const bf16x8*)(vbase + voff);
  bf16x8 vf1 = *(const bf16x8*)(vbase + voff + 16);
  bf16x8 vf2 = *(const bf16x8*)(vbase + voff + 32);
  bf16x8 vf3 = *(const bf16x8*)(vbase + voff + 48);

  f32x16 oacc = {};                    // O^T: row=channel crow(r,hi), col=q
  const int niter = NT >> 1;

  for (int t = 0; t < niter; ++t) {
    f32x16 z16 = {};
    f32x16 st0 = __builtin_amdgcn_mfma_f32_32x32x16_bf16(kf0, qfrag, z16, 0, 0, 0);
    f32x16 st1 = __builtin_amdgcn_mfma_f32_32x32x16_bf16(kf1, qfrag, z16, 0, 0, 0);

    // prefetch next pair (mask bits + K + V)
    const int adv = (t + 1 < niter) ? 1 : 0;
    const unsigned mrn0 = bq[boff + adv * 2 * SEQ];
    const unsigned mrn1 = bq[boff + adv * 2 * SEQ + SEQ];
    const bf16x8 kfn0 = *(const bf16x8*)(kbase + koff + adv * 64 * DIM);
    const bf16x8 kfn1 = *(const bf16x8*)(kbase + koff + adv * 64 * DIM + 32 * DIM);
    const int vnoff = voff + adv * 64;
    const bf16x8 vn0 = *(const bf16x8*)(vbase + vnoff);
    const bf16x8 vn1 = *(const bf16x8*)(vbase + vnoff + 16);
    const bf16x8 vn2 = *(const bf16x8*)(vbase + vnoff + 32);
    const bf16x8 vn3 = *(const bf16x8*)(vbase + vnoff + 48);

    const unsigned mrsi0 = ~(mr0 >> (hi << 2));    // inverted once per tile
    const unsigned mrsi1 = ~(mr1 >> (hi << 2));

    #pragma unroll
    for (int T = 0; T < 2; ++T) {
      const unsigned mrsi = T ? mrsi1 : mrsi0;
      #pragma unroll
      for (int sl = 0; sl < 2; ++sl) {
        float pe[8];
        #pragma unroll
        for (int j = 0; j < 8; ++j) {
          const int r = sl * 8 + j;
          const int kvc = (r & 3) + 8 * (r >> 2);    // + 4*hi via mrsi shift
          pe[j] = keep_and(fexp2(T ? st1[r] : st0[r]), mrsi, kvc);
        }
        const unsigned a0 = pkbf_fast(pe[0], pe[1]);
        const unsigned a1 = pkbf_fast(pe[2], pe[3]);
        const unsigned b0 = pkbf_fast(pe[4], pe[5]);
        const unsigned b1 = pkbf_fast(pe[6], pe[7]);
        const uint2v s0 = __builtin_amdgcn_permlane32_swap(a0, b0, false, false);
        const uint2v s1 = __builtin_amdgcn_permlane32_swap(a1, b1, false, false);
        const uint4v w = { s0.x, s1.x, s0.y, s1.y };
        const bf16x8 pfrag = __builtin_bit_cast(bf16x8, w);
        const bf16x8 vf = (T == 0) ? (sl == 0 ? vf0 : vf1)
                                   : (sl == 0 ? vf2 : vf3);
        oacc = __builtin_amdgcn_mfma_f32_32x32x16_bf16(vf, pfrag, oacc, 0, 0, 0);
      }
    }
    kf0 = kfn0; kf1 = kfn1; mr0 = mrn0; mr1 = mrn1;
    vf0 = vn0; vf1 = vn1; vf2 = vn2; vf3 = vn3;
    koff += adv * 64 * DIM;
    boff += adv * 2 * SEQ;
    voff += adv * 64;
  }

  // ---- epilogue: unnormalized partials (channels 0..15) + lsum (ch 16)
  const size_t row = (size_t)b * SEQ + qb + q;
  float* hp = parts + ((size_t)sp * 2 * SEQ + row) * DIM + h * HDK;
  f32x4 w0 = { oacc[0], oacc[1], oacc[2], oacc[3] };
  f32x4 w1 = { oacc[4], oacc[5], oacc[6], oacc[7] };
  *(f32x4*)(hp + 4 * hi)     = w0;
  *(f32x4*)(hp + 8 + 4 * hi) = w1;
  if (hi == 0)
    Lb[((size_t)sp * 2 * SEQ + row) * NHEADS + h] = oacc[8];
}

// ---------------- kernel 3: combine + output projection (fused) ------------
// grid 512 (2 blocks/CU, was 1) + NS==4 specialization so the combine's
// loads all issue in parallel (runtime-NS loop serialized load-use chains).
__global__ __launch_bounds__(256) void k_oproj(
    const float* __restrict__ parts, const float* __restrict__ Lb,
    const float* __restrict__ Wo, float* __restrict__ out, int NS) {
  __shared__ float Wl[128][128];
  __shared__ float inl[8][128];
  for (int e = threadIdx.x; e < 128 * 128; e += 256) Wl[e >> 7][e & 127] = Wo[e];
  const int r  = threadIdx.x >> 5;
  const int cg = (threadIdx.x & 31) << 2;
  const int h  = cg >> 4;
  const size_t R  = (size_t)2 * SEQ;
  const size_t rb = (size_t)blockIdx.x * 16;
  for (int pass = 0; pass < 2; ++pass) {
    __syncthreads();
    const size_t row = rb + pass * 8 + r;
    float l;
    f32x4 acc;
    if (NS == 4) {
      const float l0 = Lb[(0 * R + row) * NHEADS + h];
      const float l1 = Lb[(1 * R + row) * NHEADS + h];
      const float l2 = Lb[(2 * R + row) * NHEADS + h];
      const float l3 = Lb[(3 * R + row) * NHEADS + h];
      const f32x4 p0 = *(const f32x4*)&parts[(0 * R + row) * DIM + cg];
      const f32x4 p1 = *(const f32x4*)&parts[(1 * R + row) * DIM + cg];
      const f32x4 p2 = *(const f32x4*)&parts[(2 * R + row) * DIM + cg];
      const f32x4 p3 = *(const f32x4*)&parts[(3 * R + row) * DIM + cg];
      l = (l0 + l1) + (l2 + l3);
      acc = (p0 + p1) + (p2 + p3);
    } else {
      l = 0.f;
      acc = f32x4{0.f, 0.f, 0.f, 0.f};
      for (int sp = 0; sp < NS; ++sp) {
        l += Lb[(sp * R + row) * NHEADS + h];
        acc += *(const f32x4*)&parts[(sp * R + row) * DIM + cg];
      }
    }
    const float rinv = l > 0.f ? 1.0f / l : 0.f;
    *(f32x4*)&inl[r][cg] = acc * rinv;
    __syncthreads();
    f32x4 o = {0.f, 0.f, 0.f, 0.f};
    #pragma unroll 8
    for (int i = 0; i < 128; ++i) o += inl[r][i] * *(const f32x4*)&Wl[i][cg];
    *(f32x4*)(out + row * 128 + cg) = o;
  }
}

// ---------------- launch ---------------------------------------------------
extern "C" void kernel_launch(void* const* d_in, const int* in_sizes, int n_in,
                              void* d_out, int out_size, void* d_ws, size_t ws_size,
                              hipStream_t stream) {
  const float* qin = (const float*)d_in[0];
  const float* hin = (const float*)d_in[1];
  const void* mask = d_in[2];
  const float* Wq  = (const float*)d_in[3];
  const float* Wk  = (const float*)d_in[4];
  const float* Wv  = (const float*)d_in[5];
  const float* Wo  = (const float*)d_in[6];
  float* out = (float*)d_out;
  char* ws = (char*)d_ws;

  const size_t MAT   = (size_t)2 * SEQ * DIM;    // elems per bf16 matrix
  const size_t VMAT  = (size_t)16 * 32 * SEQ;    // Vt32 elems (4MB)
  const size_t R     = (size_t)2 * SEQ;
  const size_t BITS  = (size_t)2 * 128 * SEQ;

  int NS = 4;
  while (NS > 1) {
    size_t need = 2 * MAT * 2 + VMAT * 2 + BITS * 4 +
                  (size_t)NS * (R * DIM * 4 + R * NHEADS * 4);
    if (need <= ws_size) break;
    NS >>= 1;
  }
  const int NT = 128 / NS;

  unsigned short* Qp    = (unsigned short*)ws;
  unsigned short* Kp    = Qp + MAT;
  unsigned short* Vt32  = Kp + MAT;                    // 4 MB
  unsigned*       bits  = (unsigned*)(Vt32 + VMAT);    // 4 MB
  float*          parts = (float*)(bits + BITS);       // NS * 4 MB
  float*          Lb    = parts + (size_t)NS * R * DIM;

  k_pre<<<900, 256, 0, stream>>>(qin, hin, Wq, Wk, Wv, mask, Qp, Kp, Vt32, bits);
  k_flash<<<256 * NS, 512, 0, stream>>>(Qp, Kp, Vt32, bits, parts, Lb, NT);
  k_oproj<<<512, 256, 0, stream>>>(parts, Lb, Wo, out, NS);
}